// Round 1
// baseline (3196.969 us; speedup 1.0000x reference)
//
#include <hip/hip_runtime.h>
#include <hip/hip_bf16.h>

// Problem constants
constexpr int DIMD  = 1152;
constexpr int NHD   = 12;     // query heads
constexpr int KVHD  = 2;      // kv heads
constexpr int HDD   = 96;     // head dim
constexpr int GRPS  = 6;      // GQA group size
constexpr int SEQL  = 2048;
constexpr int BSZ4  = 4;
constexpr int MROWS = BSZ4 * SEQL;          // 8192
constexpr int NQKV  = DIMD + 2 * KVHD * HDD; // 1536
constexpr float SCALE = 0.10206207261596577f; // 96^-0.5

// ---------------------------------------------------------------------------
// Kernel 1: fused QKV projection GEMM + bias + RoPE + scatter to [b,h,s,d]
// C[m,n] = sum_k x[m,k] * W[n,k]   (W = q_w rows 0..1151, kv_w rows 1152..1535)
// 64x64 tile, 256 threads, 4x4 per thread, BK=16.
// ---------------------------------------------------------------------------
__global__ __launch_bounds__(256) void qkv_gemm_kernel(
    const float* __restrict__ x,   const float* __restrict__ qw,
    const float* __restrict__ qb,  const float* __restrict__ kvw,
    const float* __restrict__ kvb, const int* __restrict__ start_pos,
    float* __restrict__ Qo, float* __restrict__ Ko, float* __restrict__ Vo)
{
    __shared__ float As[64][17];   // +1 pad: 4-distinct-bank reads for row groups
    __shared__ float Bs[64][17];

    const int tid = threadIdx.x;
    const int tx = tid & 15, ty = tid >> 4;
    const int m0 = blockIdx.y * 64;
    const int n0 = blockIdx.x * 64;

    float acc[4][4] = {};

    for (int k0 = 0; k0 < DIMD; k0 += 16) {
        #pragma unroll
        for (int i = 0; i < 4; i++) {
            int idx = tid + 256 * i;       // 0..1023
            int r = idx >> 4, c = idx & 15;
            As[r][c] = x[(size_t)(m0 + r) * DIMD + k0 + c];
            int n = n0 + r;                // branch uniform per block (1152 % 64 == 0)
            Bs[r][c] = (n < DIMD) ? qw[(size_t)n * DIMD + k0 + c]
                                  : kvw[(size_t)(n - DIMD) * DIMD + k0 + c];
        }
        __syncthreads();
        #pragma unroll
        for (int kk = 0; kk < 16; kk++) {
            float a[4], b[4];
            #pragma unroll
            for (int i = 0; i < 4; i++) a[i] = As[ty * 4 + i][kk];
            #pragma unroll
            for (int j = 0; j < 4; j++) b[j] = Bs[tx * 4 + j][kk];
            #pragma unroll
            for (int i = 0; i < 4; i++)
                #pragma unroll
                for (int j = 0; j < 4; j++)
                    acc[i][j] = fmaf(a[i], b[j], acc[i][j]);
        }
        __syncthreads();
    }

    // Epilogue: bias, RoPE (interleaved pairs), scatter.
    const int sp = *start_pos;
    #pragma unroll
    for (int jp = 0; jp < 2; jp++) {
        const int j = jp * 2;
        const int n = n0 + tx * 4 + j;     // even
        const bool isQ = (n < DIMD);
        int h = 0, d = 0, ikv = 0, i2 = 0;
        float be, bo;
        if (isQ) {
            h = n / HDD; d = n % HDD;
            be = qb[n]; bo = qb[n + 1];
        } else {
            int jj = n - DIMD;             // [0,384): (i2, ikv, d)
            i2 = jj / (KVHD * HDD);
            ikv = (jj / HDD) & (KVHD - 1);
            d = jj % HDD;                  // even
            be = kvb[jj]; bo = kvb[jj + 1];
        }
        const bool doRope = isQ || (i2 == 0);
        float th = 0.0f;
        if (doRope) th = powf(10000.0f, -(float)d * (1.0f / (float)HDD));
        #pragma unroll
        for (int i = 0; i < 4; i++) {
            int m = m0 + ty * 4 + i;
            int b = m >> 11;               // m / 2048
            int s = m & (SEQL - 1);
            float ve = acc[i][j] + be, vo = acc[i][j + 1] + bo;
            float oe = ve, oo = vo;
            if (doRope) {
                float ang = (float)(s + sp) * th;
                float sn, cs; sincosf(ang, &sn, &cs);
                oe = ve * cs - vo * sn;
                oo = vo * cs + ve * sn;
            }
            float2 o2 = make_float2(oe, oo);
            if (isQ) {
                *(float2*)(Qo + ((((size_t)b * NHD + h) * SEQL + s) * HDD + d)) = o2;
            } else {
                size_t off = (((size_t)b * KVHD + ikv) * SEQL + s) * HDD + d;
                if (i2 == 0) *(float2*)(Ko + off) = o2;
                else         *(float2*)(Vo + off) = o2;
            }
        }
    }
}

// ---------------------------------------------------------------------------
// Kernel 2: causal flash attention, fp32. One WG = (b, h, 32 q-rows).
// TQ=32, TK=64. Online softmax. K and V share one LDS buffer.
// LDS: Qs 12.4KB + KVs 24.8KB + Ps 8.3KB + state ~0.4KB = ~46KB -> 3 WG/CU.
// ---------------------------------------------------------------------------
__global__ __launch_bounds__(256) void attn_kernel(
    const float* __restrict__ Qi, const float* __restrict__ Ki,
    const float* __restrict__ Vi, float* __restrict__ AO)
{
    __shared__ float Qs[32][97];
    __shared__ float KVs[64][97];
    __shared__ float Ps[32][65];
    __shared__ float mrow[32], lrow[32], arow[32];

    const int tid = threadIdx.x;
    const int qt = blockIdx.x;     // 0..63  (q-tile of 32 rows)
    const int h  = blockIdx.y;     // 0..11
    const int b  = blockIdx.z;     // 0..3
    const int kvh = h / GRPS;
    const int rg = tid >> 4;       // 0..15 -> rows {2rg, 2rg+1}
    const int cg = tid & 15;       // 0..15

    const float* Qbase = Qi + (((size_t)b * NHD + h) * SEQL + (size_t)qt * 32) * HDD;
    const float* Kbase = Ki + (((size_t)b * KVHD + kvh) * SEQL) * HDD;
    const float* Vbase = Vi + (((size_t)b * KVHD + kvh) * SEQL) * HDD;

    // Stage Q tile (32x96 = 3072 elems, 12/thread, linear -> coalesced)
    #pragma unroll
    for (int i = 0; i < 12; i++) {
        int idx = tid + 256 * i;
        Qs[idx / 96][idx % 96] = Qbase[idx];
    }
    if (tid < 32) { mrow[tid] = -1e30f; lrow[tid] = 0.0f; }

    float acc[2][6] = {};   // O rows {2rg+i}, cols {6cg+j}

    const int nkb = (qt >> 1) + 1;   // causal: k-blocks of 64 up to row qt*32+31
    for (int kb = 0; kb < nkb; kb++) {
        const int k0 = kb * 64;
        // Stage K tile (64x96 = 6144, 24/thread)
        #pragma unroll
        for (int i = 0; i < 24; i++) {
            int idx = tid + 256 * i;
            KVs[idx / 96][idx % 96] = Kbase[(size_t)k0 * HDD + idx];
        }
        __syncthreads();   // K visible (covers Q/state on first iter)

        // Scores: 32x64 tile, 2x4 per thread
        float sacc[2][4] = {};
        #pragma unroll 4
        for (int k = 0; k < HDD; k++) {
            float a0 = Qs[2 * rg + 0][k];
            float a1 = Qs[2 * rg + 1][k];
            float b0 = KVs[4 * cg + 0][k];
            float b1 = KVs[4 * cg + 1][k];
            float b2 = KVs[4 * cg + 2][k];
            float b3 = KVs[4 * cg + 3][k];
            sacc[0][0] = fmaf(a0, b0, sacc[0][0]);
            sacc[0][1] = fmaf(a0, b1, sacc[0][1]);
            sacc[0][2] = fmaf(a0, b2, sacc[0][2]);
            sacc[0][3] = fmaf(a0, b3, sacc[0][3]);
            sacc[1][0] = fmaf(a1, b0, sacc[1][0]);
            sacc[1][1] = fmaf(a1, b1, sacc[1][1]);
            sacc[1][2] = fmaf(a1, b2, sacc[1][2]);
            sacc[1][3] = fmaf(a1, b3, sacc[1][3]);
        }
        // Scale + causal mask -> Ps
        #pragma unroll
        for (int i = 0; i < 2; i++) {
            int qpos = qt * 32 + 2 * rg + i;
            #pragma unroll
            for (int jj = 0; jj < 4; jj++) {
                int kpos = k0 + 4 * cg + jj;
                Ps[2 * rg + i][4 * cg + jj] =
                    (kpos <= qpos) ? sacc[i][jj] * SCALE : -1e9f;
            }
        }
        __syncthreads();   // scores done; KVs free

        // Stage V tile (overwrites K) — concurrent with softmax stats below
        #pragma unroll
        for (int i = 0; i < 24; i++) {
            int idx = tid + 256 * i;
            KVs[idx / 96][idx % 96] = Vbase[(size_t)k0 * HDD + idx];
        }
        // Row stats: one thread per q-row
        if (tid < 32) {
            float mo = mrow[tid];
            float mx = mo;
            for (int j2 = 0; j2 < 64; j2++) mx = fmaxf(mx, Ps[tid][j2]);
            float al = expf(mo - mx);   // first block: exp(-1e30 - mx) = 0
            float sum = 0.0f;
            for (int j2 = 0; j2 < 64; j2++) {
                float pv = expf(Ps[tid][j2] - mx);
                Ps[tid][j2] = pv;
                sum += pv;
            }
            mrow[tid] = mx;
            lrow[tid] = lrow[tid] * al + sum;
            arow[tid] = al;
        }
        __syncthreads();   // V + P + alpha ready

        // Rescale and accumulate O += P @ V
        float al0 = arow[2 * rg + 0];
        float al1 = arow[2 * rg + 1];
        #pragma unroll
        for (int jj = 0; jj < 6; jj++) { acc[0][jj] *= al0; acc[1][jj] *= al1; }
        #pragma unroll 2
        for (int t2 = 0; t2 < 64; t2++) {
            float p0 = Ps[2 * rg + 0][t2];
            float p1 = Ps[2 * rg + 1][t2];
            #pragma unroll
            for (int jj = 0; jj < 6; jj++) {
                float vv = KVs[t2][6 * cg + jj];
                acc[0][jj] = fmaf(p0, vv, acc[0][jj]);
                acc[1][jj] = fmaf(p1, vv, acc[1][jj]);
            }
        }
        __syncthreads();   // protect KVs/Ps before next iteration
    }

    // Normalize and write attn_out[b, s, h*96 + c] (row-major 8192x1152)
    float li0 = 1.0f / lrow[2 * rg + 0];
    float li1 = 1.0f / lrow[2 * rg + 1];
    #pragma unroll
    for (int i = 0; i < 2; i++) {
        float li = (i == 0) ? li0 : li1;
        int s = qt * 32 + 2 * rg + i;
        float* dst = AO + ((size_t)b * SEQL + s) * DIMD + h * HDD + 6 * cg;
        #pragma unroll
        for (int jj = 0; jj < 6; jj += 2)
            *(float2*)(dst + jj) =
                make_float2(acc[i][jj] * li, acc[i][jj + 1] * li);
    }
}

// ---------------------------------------------------------------------------
// Kernel 3: output projection  out[m,n] = sum_k AO[m,k]*wo_w[n,k] + wo_b[n]
// ---------------------------------------------------------------------------
__global__ __launch_bounds__(256) void out_gemm_kernel(
    const float* __restrict__ A, const float* __restrict__ W,
    const float* __restrict__ wob, float* __restrict__ out)
{
    __shared__ float As[64][17];
    __shared__ float Bs[64][17];

    const int tid = threadIdx.x;
    const int tx = tid & 15, ty = tid >> 4;
    const int m0 = blockIdx.y * 64;
    const int n0 = blockIdx.x * 64;

    float acc[4][4] = {};

    for (int k0 = 0; k0 < DIMD; k0 += 16) {
        #pragma unroll
        for (int i = 0; i < 4; i++) {
            int idx = tid + 256 * i;
            int r = idx >> 4, c = idx & 15;
            As[r][c] = A[(size_t)(m0 + r) * DIMD + k0 + c];
            Bs[r][c] = W[(size_t)(n0 + r) * DIMD + k0 + c];
        }
        __syncthreads();
        #pragma unroll
        for (int kk = 0; kk < 16; kk++) {
            float a[4], b[4];
            #pragma unroll
            for (int i = 0; i < 4; i++) a[i] = As[ty * 4 + i][kk];
            #pragma unroll
            for (int j = 0; j < 4; j++) b[j] = Bs[tx * 4 + j][kk];
            #pragma unroll
            for (int i = 0; i < 4; i++)
                #pragma unroll
                for (int j = 0; j < 4; j++)
                    acc[i][j] = fmaf(a[i], b[j], acc[i][j]);
        }
        __syncthreads();
    }

    #pragma unroll
    for (int i = 0; i < 4; i++) {
        int m = m0 + ty * 4 + i;
        int n = n0 + tx * 4;
        float4 o;
        o.x = acc[i][0] + wob[n + 0];
        o.y = acc[i][1] + wob[n + 1];
        o.z = acc[i][2] + wob[n + 2];
        o.w = acc[i][3] + wob[n + 3];
        *(float4*)(out + (size_t)m * DIMD + n) = o;
    }
}

// ---------------------------------------------------------------------------
extern "C" void kernel_launch(void* const* d_in, const int* in_sizes, int n_in,
                              void* d_out, int out_size, void* d_ws, size_t ws_size,
                              hipStream_t stream)
{
    const float* x   = (const float*)d_in[0];
    // d_in[1] = mask: exactly triu(-1e9, k=1) -> implemented as causal predicate
    const float* qw  = (const float*)d_in[2];
    const float* qb  = (const float*)d_in[3];
    const float* kvw = (const float*)d_in[4];
    const float* kvb = (const float*)d_in[5];
    const float* wow = (const float*)d_in[6];
    const float* wob = (const float*)d_in[7];
    const int*   sp  = (const int*)d_in[8];

    float* ws = (float*)d_ws;
    const size_t qElems  = (size_t)BSZ4 * NHD * SEQL * HDD;   // 9,437,184
    const size_t kvElems = (size_t)BSZ4 * KVHD * SEQL * HDD;  // 1,572,864
    float* Q  = ws;
    float* K  = Q + qElems;
    float* V  = K + kvElems;
    float* AO = V + kvElems;   // 8192 x 1152; total ws use = 88 MB

    qkv_gemm_kernel<<<dim3(NQKV / 64, MROWS / 64, 1), 256, 0, stream>>>(
        x, qw, qb, kvw, kvb, sp, Q, K, V);
    attn_kernel<<<dim3(SEQL / 32, NHD, BSZ4), 256, 0, stream>>>(Q, K, V, AO);
    out_gemm_kernel<<<dim3(DIMD / 64, MROWS / 64, 1), 256, 0, stream>>>(
        AO, wow, wob, (float*)d_out);
}

// Round 2
// 1394.339 us; speedup vs baseline: 2.2928x; 2.2928x over previous
//
#include <hip/hip_runtime.h>
#include <hip/hip_bf16.h>

// Problem constants
constexpr int DIMD  = 1152;
constexpr int NHD   = 12;     // query heads
constexpr int KVHD  = 2;      // kv heads
constexpr int HDD   = 96;     // head dim
constexpr int GRPS  = 6;      // GQA group size
constexpr int SEQL  = 2048;
constexpr int BSZ4  = 4;
constexpr int MROWS = BSZ4 * SEQL;           // 8192
constexpr int NQKV  = DIMD + 2 * KVHD * HDD; // 1536
constexpr float SCALE = 0.10206207261596577f; // 96^-0.5

typedef short  bf16x8 __attribute__((ext_vector_type(8)));
typedef float  f32x4  __attribute__((ext_vector_type(4)));

__device__ __forceinline__ unsigned short f2bf(float f) {
    unsigned int u = __builtin_bit_cast(unsigned int, f);
    u += 0x7fff + ((u >> 16) & 1);   // RNE (p>=0 here, no NaN concerns)
    return (unsigned short)(u >> 16);
}

// ---------------------------------------------------------------------------
// Kernel 1: fused QKV projection GEMM (fp32 math) + bias + RoPE + bf16 scatter
// Q  -> bf16 [b][h][s][96]
// K  -> bf16 [b][kvh][s][96]
// V  -> bf16 TRANSPOSED [b][kvh][96][s]   (for MFMA B-fragment reads)
// ---------------------------------------------------------------------------
__global__ __launch_bounds__(256) void qkv_gemm_kernel(
    const float* __restrict__ x,   const float* __restrict__ qw,
    const float* __restrict__ qb,  const float* __restrict__ kvw,
    const float* __restrict__ kvb, const int* __restrict__ start_pos,
    unsigned short* __restrict__ Qo, unsigned short* __restrict__ Ko,
    unsigned short* __restrict__ VTo)
{
    __shared__ float As[64][17];
    __shared__ float Bs[64][17];

    const int tid = threadIdx.x;
    const int tx = tid & 15, ty = tid >> 4;
    const int m0 = blockIdx.y * 64;
    const int n0 = blockIdx.x * 64;

    float acc[4][4] = {};

    for (int k0 = 0; k0 < DIMD; k0 += 16) {
        #pragma unroll
        for (int i = 0; i < 4; i++) {
            int idx = tid + 256 * i;
            int r = idx >> 4, c = idx & 15;
            As[r][c] = x[(size_t)(m0 + r) * DIMD + k0 + c];
            int n = n0 + r;
            Bs[r][c] = (n < DIMD) ? qw[(size_t)n * DIMD + k0 + c]
                                  : kvw[(size_t)(n - DIMD) * DIMD + k0 + c];
        }
        __syncthreads();
        #pragma unroll
        for (int kk = 0; kk < 16; kk++) {
            float a[4], b[4];
            #pragma unroll
            for (int i = 0; i < 4; i++) a[i] = As[ty * 4 + i][kk];
            #pragma unroll
            for (int j = 0; j < 4; j++) b[j] = Bs[tx * 4 + j][kk];
            #pragma unroll
            for (int i = 0; i < 4; i++)
                #pragma unroll
                for (int j = 0; j < 4; j++)
                    acc[i][j] = fmaf(a[i], b[j], acc[i][j]);
        }
        __syncthreads();
    }

    const int sp = *start_pos;
    #pragma unroll
    for (int jp = 0; jp < 2; jp++) {
        const int j = jp * 2;
        const int n = n0 + tx * 4 + j;     // even
        const bool isQ = (n < DIMD);
        int h = 0, d = 0, ikv = 0, i2 = 0;
        float be, bo;
        if (isQ) {
            h = n / HDD; d = n % HDD;
            be = qb[n]; bo = qb[n + 1];
        } else {
            int jj = n - DIMD;
            i2 = jj / (KVHD * HDD);
            ikv = (jj / HDD) & (KVHD - 1);
            d = jj % HDD;
            be = kvb[jj]; bo = kvb[jj + 1];
        }
        const bool doRope = isQ || (i2 == 0);
        float th = 0.0f;
        if (doRope) th = powf(10000.0f, -(float)d * (1.0f / (float)HDD));
        #pragma unroll
        for (int i = 0; i < 4; i++) {
            int m = m0 + ty * 4 + i;
            int b = m >> 11;
            int s = m & (SEQL - 1);
            float ve = acc[i][j] + be, vo = acc[i][j + 1] + bo;
            float oe = ve, oo = vo;
            if (doRope) {
                float ang = (float)(s + sp) * th;
                float sn, cs; sincosf(ang, &sn, &cs);
                oe = ve * cs - vo * sn;
                oo = vo * cs + ve * sn;
            }
            unsigned int packed =
                (unsigned int)f2bf(oe) | ((unsigned int)f2bf(oo) << 16);
            if (isQ) {
                size_t off = (((size_t)b * NHD + h) * SEQL + s) * HDD + d;
                *(unsigned int*)(Qo + off) = packed;
            } else if (i2 == 0) {
                size_t off = (((size_t)b * KVHD + ikv) * SEQL + s) * HDD + d;
                *(unsigned int*)(Ko + off) = packed;
            } else {
                size_t base = (((size_t)b * KVHD + ikv) * HDD + d) * SEQL + s;
                VTo[base]        = f2bf(oe);
                VTo[base + SEQL] = f2bf(oo);
            }
        }
    }
}

// ---------------------------------------------------------------------------
// Kernel 2: bf16 MFMA causal flash attention.
// WG = 256 thr = 4 waves; 64 q-rows per WG (16 per wave); TK = 64.
// Q frags in registers. K tile + V^T tile in LDS. P: C-layout -> LDS -> A-layout
// (wave-private, wave_barrier only). Online softmax via quad shuffles.
// LDS: Ks 13312 + VTs 13824 + Ps 9216 = 36352 B -> 4 WG/CU.
// ---------------------------------------------------------------------------
__global__ __launch_bounds__(256) void attn_mfma_kernel(
    const unsigned short* __restrict__ Q, const unsigned short* __restrict__ K,
    const unsigned short* __restrict__ VT, float* __restrict__ AO)
{
    __shared__ unsigned short Ks[64][104];   // row stride 104 -> 2-way max
    __shared__ unsigned short VTs[96][72];
    __shared__ unsigned short Ps[4][16][72];

    const int tid  = threadIdx.x;
    const int w    = tid >> 6;
    const int lane = tid & 63;
    const int l16  = lane & 15;
    const int quad = lane >> 4;
    const int qt   = (gridDim.x - 1) - blockIdx.x;  // heavy tiles first
    const int h    = blockIdx.y;
    const int b    = blockIdx.z;
    const int kvh  = h / GRPS;

    const unsigned short* Qbase  = Q  + (((size_t)b * NHD  + h)   * SEQL) * HDD;
    const unsigned short* Kbase  = K  + (((size_t)b * KVHD + kvh) * SEQL) * HDD;
    const unsigned short* VTbase = VT + (((size_t)b * KVHD + kvh) * HDD)  * SEQL;

    // Q fragments: A[m=l16][k=quad*8+j+32*ki]
    bf16x8 qf[3];
    {
        const int qrow = qt * 64 + w * 16 + l16;
        const unsigned short* qp = Qbase + (size_t)qrow * HDD + quad * 8;
        qf[0] = *(const bf16x8*)(qp);
        qf[1] = *(const bf16x8*)(qp + 32);
        qf[2] = *(const bf16x8*)(qp + 64);
    }

    float m_r[4], l_r[4];
    #pragma unroll
    for (int r = 0; r < 4; r++) { m_r[r] = -1e30f; l_r[r] = 0.0f; }
    f32x4 oacc[6];
    #pragma unroll
    for (int n = 0; n < 6; n++) oacc[n] = (f32x4){0.f, 0.f, 0.f, 0.f};

    const int nkb = qt + 1;
    for (int kb = 0; kb < nkb; kb++) {
        const int k0 = kb * 64;
        // ---- stage K tile (64 x 96) ----
        {
            const int r = tid >> 2, c = (tid & 3) * 24;
            const unsigned short* src = Kbase + (size_t)(k0 + r) * HDD + c;
            unsigned short* dst = &Ks[r][c];
            *(bf16x8*)(dst)      = *(const bf16x8*)(src);
            *(bf16x8*)(dst + 8)  = *(const bf16x8*)(src + 8);
            *(bf16x8*)(dst + 16) = *(const bf16x8*)(src + 16);
        }
        // ---- stage V^T tile (96 x 64) ----
        {
            const int rr = tid >> 3, c = (tid & 7) * 8;
            #pragma unroll
            for (int p = 0; p < 3; p++) {
                const int r = p * 32 + rr;
                *(bf16x8*)(&VTs[r][c]) =
                    *(const bf16x8*)(VTbase + (size_t)r * SEQL + k0 + c);
            }
        }
        __syncthreads();

        // ---- S = Q K^T : 4 16x16 tiles ----
        f32x4 s[4];
        #pragma unroll
        for (int n = 0; n < 4; n++) {
            const unsigned short* kr = &Ks[n * 16 + l16][quad * 8];
            bf16x8 b0 = *(const bf16x8*)(kr);
            bf16x8 b1 = *(const bf16x8*)(kr + 32);
            bf16x8 b2 = *(const bf16x8*)(kr + 64);
            f32x4 acc = (f32x4){0.f, 0.f, 0.f, 0.f};
            acc = __builtin_amdgcn_mfma_f32_16x16x32_bf16(qf[0], b0, acc, 0, 0, 0);
            acc = __builtin_amdgcn_mfma_f32_16x16x32_bf16(qf[1], b1, acc, 0, 0, 0);
            acc = __builtin_amdgcn_mfma_f32_16x16x32_bf16(qf[2], b2, acc, 0, 0, 0);
            s[n] = acc;
        }

        // ---- online softmax (rows quad*4+r, col l16 within each n-tile) ----
        const int qabs = qt * 64 + w * 16 + quad * 4;
        const bool diag = (kb == qt);
        float alpha[4];
        #pragma unroll
        for (int r = 0; r < 4; r++) {
            float sv[4];
            #pragma unroll
            for (int n = 0; n < 4; n++) {
                float v = s[n][r] * SCALE;
                if (diag && (k0 + n * 16 + l16 > qabs + r)) v = -1e30f;
                sv[n] = v;
            }
            float mx = fmaxf(fmaxf(sv[0], sv[1]), fmaxf(sv[2], sv[3]));
            #pragma unroll
            for (int off = 1; off < 16; off <<= 1)
                mx = fmaxf(mx, __shfl_xor(mx, off, 64));
            const float mnew = fmaxf(m_r[r], mx);
            const float al = __expf(m_r[r] - mnew);
            float p[4], sum = 0.0f;
            #pragma unroll
            for (int n = 0; n < 4; n++) { p[n] = __expf(sv[n] - mnew); sum += p[n]; }
            #pragma unroll
            for (int off = 1; off < 16; off <<= 1)
                sum += __shfl_xor(sum, off, 64);
            l_r[r] = l_r[r] * al + sum;
            m_r[r] = mnew;
            alpha[r] = al;
            #pragma unroll
            for (int n = 0; n < 4; n++)
                Ps[w][quad * 4 + r][n * 16 + l16] = f2bf(p[n]);
        }
        __builtin_amdgcn_wave_barrier();   // P write -> P read, same wave, in-order DS

        // ---- O = diag(alpha) O + P V ----
        bf16x8 pa0 = *(const bf16x8*)(&Ps[w][l16][quad * 8]);
        bf16x8 pa1 = *(const bf16x8*)(&Ps[w][l16][32 + quad * 8]);
        #pragma unroll
        for (int n = 0; n < 6; n++) {
            const unsigned short* vr = &VTs[n * 16 + l16][quad * 8];
            bf16x8 vb0 = *(const bf16x8*)(vr);
            bf16x8 vb1 = *(const bf16x8*)(vr + 32);
            f32x4 acc = oacc[n];
            #pragma unroll
            for (int r = 0; r < 4; r++) acc[r] *= alpha[r];
            acc = __builtin_amdgcn_mfma_f32_16x16x32_bf16(pa0, vb0, acc, 0, 0, 0);
            acc = __builtin_amdgcn_mfma_f32_16x16x32_bf16(pa1, vb1, acc, 0, 0, 0);
            oacc[n] = acc;
        }
        __syncthreads();   // protect Ks/VTs before next stage
    }

    // ---- epilogue: normalize, write AO fp32 [8192][1152] ----
    float inv_l[4];
    #pragma unroll
    for (int r = 0; r < 4; r++) inv_l[r] = 1.0f / l_r[r];
    const int srow = qt * 64 + w * 16 + quad * 4;
    #pragma unroll
    for (int n = 0; n < 6; n++) {
        #pragma unroll
        for (int r = 0; r < 4; r++) {
            AO[((size_t)b * SEQL + srow + r) * DIMD + h * HDD + n * 16 + l16] =
                oacc[n][r] * inv_l[r];
        }
    }
}

// ---------------------------------------------------------------------------
// Kernel 3: output projection  out[m,n] = sum_k AO[m,k]*wo_w[n,k] + wo_b[n]
// ---------------------------------------------------------------------------
__global__ __launch_bounds__(256) void out_gemm_kernel(
    const float* __restrict__ A, const float* __restrict__ W,
    const float* __restrict__ wob, float* __restrict__ out)
{
    __shared__ float As[64][17];
    __shared__ float Bs[64][17];

    const int tid = threadIdx.x;
    const int tx = tid & 15, ty = tid >> 4;
    const int m0 = blockIdx.y * 64;
    const int n0 = blockIdx.x * 64;

    float acc[4][4] = {};

    for (int k0 = 0; k0 < DIMD; k0 += 16) {
        #pragma unroll
        for (int i = 0; i < 4; i++) {
            int idx = tid + 256 * i;
            int r = idx >> 4, c = idx & 15;
            As[r][c] = A[(size_t)(m0 + r) * DIMD + k0 + c];
            Bs[r][c] = W[(size_t)(n0 + r) * DIMD + k0 + c];
        }
        __syncthreads();
        #pragma unroll
        for (int kk = 0; kk < 16; kk++) {
            float a[4], b[4];
            #pragma unroll
            for (int i = 0; i < 4; i++) a[i] = As[ty * 4 + i][kk];
            #pragma unroll
            for (int j = 0; j < 4; j++) b[j] = Bs[tx * 4 + j][kk];
            #pragma unroll
            for (int i = 0; i < 4; i++)
                #pragma unroll
                for (int j = 0; j < 4; j++)
                    acc[i][j] = fmaf(a[i], b[j], acc[i][j]);
        }
        __syncthreads();
    }

    #pragma unroll
    for (int i = 0; i < 4; i++) {
        int m = m0 + ty * 4 + i;
        int n = n0 + tx * 4;
        float4 o;
        o.x = acc[i][0] + wob[n + 0];
        o.y = acc[i][1] + wob[n + 1];
        o.z = acc[i][2] + wob[n + 2];
        o.w = acc[i][3] + wob[n + 3];
        *(float4*)(out + (size_t)m * DIMD + n) = o;
    }
}

// ---------------------------------------------------------------------------
extern "C" void kernel_launch(void* const* d_in, const int* in_sizes, int n_in,
                              void* d_out, int out_size, void* d_ws, size_t ws_size,
                              hipStream_t stream)
{
    const float* x   = (const float*)d_in[0];
    // d_in[1] = mask: exactly triu(-1e9, k=1) -> implemented as causal predicate
    const float* qw  = (const float*)d_in[2];
    const float* qb  = (const float*)d_in[3];
    const float* kvw = (const float*)d_in[4];
    const float* kvb = (const float*)d_in[5];
    const float* wow = (const float*)d_in[6];
    const float* wob = (const float*)d_in[7];
    const int*   sp  = (const int*)d_in[8];

    const size_t qElems  = (size_t)BSZ4 * NHD  * SEQL * HDD;  // 9,437,184
    const size_t kvElems = (size_t)BSZ4 * KVHD * SEQL * HDD;  // 1,572,864

    float* AO = (float*)d_ws;                                  // 8192x1152 fp32
    unsigned short* Q16  = (unsigned short*)(AO + (size_t)MROWS * DIMD);
    unsigned short* K16  = Q16 + qElems;
    unsigned short* VT16 = K16 + kvElems;                      // total ~63 MB

    qkv_gemm_kernel<<<dim3(NQKV / 64, MROWS / 64, 1), 256, 0, stream>>>(
        x, qw, qb, kvw, kvb, sp, Q16, K16, VT16);
    attn_mfma_kernel<<<dim3(SEQL / 64, NHD, BSZ4), 256, 0, stream>>>(
        Q16, K16, VT16, AO);
    out_gemm_kernel<<<dim3(DIMD / 64, MROWS / 64, 1), 256, 0, stream>>>(
        AO, wow, wob, (float*)d_out);
}

// Round 3
// 487.042 us; speedup vs baseline: 6.5640x; 2.8629x over previous
//
#include <hip/hip_runtime.h>
#include <hip/hip_bf16.h>

// Problem constants
constexpr int DIMD  = 1152;
constexpr int NHD   = 12;     // query heads
constexpr int KVHD  = 2;      // kv heads
constexpr int HDD   = 96;     // head dim
constexpr int GRPS  = 6;      // GQA group size
constexpr int SEQL  = 2048;
constexpr int BSZ4  = 4;
constexpr int MROWS = BSZ4 * SEQL;           // 8192
constexpr int NQKV  = DIMD + 2 * KVHD * HDD; // 1536
constexpr float SCALE = 0.10206207261596577f; // 96^-0.5

typedef short  bf16x8 __attribute__((ext_vector_type(8)));
typedef float  f32x4  __attribute__((ext_vector_type(4)));

typedef __attribute__((address_space(3))) unsigned int       lds_u32_t;
typedef __attribute__((address_space(1))) const unsigned int glb_u32_t;

__device__ __forceinline__ void gload16(const unsigned short* g, unsigned short* l) {
    // async global->LDS, 16B/lane; LDS dest is wave-uniform base + lane*16
    __builtin_amdgcn_global_load_lds((glb_u32_t*)(const void*)g,
                                     (lds_u32_t*)(void*)l, 16, 0, 0);
}

__device__ __forceinline__ unsigned short f2bf(float f) {
    unsigned int u = __builtin_bit_cast(unsigned int, f);
    u += 0x7fff + ((u >> 16) & 1);   // RNE
    return (unsigned short)(u >> 16);
}

// ---------------------------------------------------------------------------
// fp32 -> bf16 elementwise convert (float4 in, ushort4 out)
// ---------------------------------------------------------------------------
__global__ __launch_bounds__(256) void cvt_bf16_kernel(
    const float4* __restrict__ src, ushort4* __restrict__ dst, int n4)
{
    int i = blockIdx.x * 256 + threadIdx.x;
    if (i < n4) {
        float4 f = src[i];
        ushort4 o;
        o.x = f2bf(f.x); o.y = f2bf(f.y); o.z = f2bf(f.z); o.w = f2bf(f.w);
        dst[i] = o;
    }
}

// ---------------------------------------------------------------------------
// Kernel 1: QKV projection, bf16 MFMA (m97 structure: 128x128 tile, BK=32,
// global_load_lds staging, 2-barrier K-loop). Epilogue: fp32 bias + RoPE
// (pair exchange via shfl_xor lane^1) + bf16 scatter to Q / K / V^T.
// ---------------------------------------------------------------------------
__global__ __launch_bounds__(256) void qkv_mfma_kernel(
    const unsigned short* __restrict__ xb,  const unsigned short* __restrict__ qwb,
    const unsigned short* __restrict__ kvwb,
    const float* __restrict__ qb,  const float* __restrict__ kvb,
    const int* __restrict__ start_pos,
    unsigned short* __restrict__ Qo, unsigned short* __restrict__ Ko,
    unsigned short* __restrict__ VTo)
{
    __shared__ __align__(16) unsigned short As[128 * 32];
    __shared__ __align__(16) unsigned short Bs[128 * 32];

    const int tid  = threadIdx.x;
    const int w    = tid >> 6;
    const int lane = tid & 63;
    const int l16  = lane & 15;
    const int quad = lane >> 4;
    const int wm   = w >> 1, wn = w & 1;
    const int m0   = blockIdx.y * 128;
    const int n0   = blockIdx.x * 128;

    // Region is block-uniform for staging (128-row span never straddles qw/kvw)
    const unsigned short* Abase = xb + (size_t)m0 * DIMD;
    const unsigned short* Bbase = (n0 < DIMD)
        ? qwb  + (size_t)n0 * DIMD
        : kvwb + (size_t)(n0 - DIMD) * DIMD;

    const int srow = w * 16 + (lane >> 2);   // staging row (per instr half)
    const int scol = (lane & 3) * 8;         // staging col (8 bf16 = 16B)

    f32x4 acc[4][4];
    #pragma unroll
    for (int mi = 0; mi < 4; mi++)
        #pragma unroll
        for (int ni = 0; ni < 4; ni++) acc[mi][ni] = (f32x4){0.f, 0.f, 0.f, 0.f};

    for (int k0 = 0; k0 < DIMD; k0 += 32) {
        gload16(Abase + (size_t)srow        * DIMD + k0 + scol, &As[w * 512]);
        gload16(Abase + (size_t)(srow + 64) * DIMD + k0 + scol, &As[2048 + w * 512]);
        gload16(Bbase + (size_t)srow        * DIMD + k0 + scol, &Bs[w * 512]);
        gload16(Bbase + (size_t)(srow + 64) * DIMD + k0 + scol, &Bs[2048 + w * 512]);
        __syncthreads();
        bf16x8 af[4], bfr[4];
        #pragma unroll
        for (int mi = 0; mi < 4; mi++)
            af[mi] = *(const bf16x8*)&As[(wm * 64 + mi * 16 + l16) * 32 + quad * 8];
        #pragma unroll
        for (int ni = 0; ni < 4; ni++)
            bfr[ni] = *(const bf16x8*)&Bs[(wn * 64 + ni * 16 + l16) * 32 + quad * 8];
        #pragma unroll
        for (int mi = 0; mi < 4; mi++)
            #pragma unroll
            for (int ni = 0; ni < 4; ni++)
                acc[mi][ni] = __builtin_amdgcn_mfma_f32_16x16x32_bf16(
                    af[mi], bfr[ni], acc[mi][ni], 0, 0, 0);
        __syncthreads();
    }

    // Epilogue. C layout: col n = +l16, row m = +quad*4+r.
    const int sp = *start_pos;
    #pragma unroll
    for (int ni = 0; ni < 4; ni++) {
        const int n   = n0 + wn * 64 + ni * 16 + l16;
        const bool isQ = (n < DIMD);
        const int jj  = n - DIMD;
        const bool isK = !isQ && (jj < KVHD * HDD);
        const int d   = isQ ? (n % HDD) : (jj % HDD);
        const int hh  = isQ ? (n / HDD) : ((jj / HDD) & 1);
        const float bias = isQ ? qb[n] : kvb[jj];
        const bool doRope = isQ || isK;   // uniform across the wave (16-col tile in one region)
        const int de = d & ~1;
        const float th = doRope ? powf(10000.0f, -(float)de / 96.0f) : 0.0f;
        const float sg = (n & 1) ? 1.0f : -1.0f;
        #pragma unroll
        for (int mi = 0; mi < 4; mi++) {
            #pragma unroll
            for (int r = 0; r < 4; r++) {
                const int m = m0 + wm * 64 + mi * 16 + quad * 4 + r;
                const int b = m >> 11;
                const int s = m & (SEQL - 1);
                float v  = acc[mi][ni][r] + bias;
                float pv = __shfl_xor(v, 1, 64);   // partner feature (n^1), same rows
                float o = v;
                if (doRope) {
                    float ang = (float)(s + sp) * th;
                    float sn, cs; sincosf(ang, &sn, &cs);
                    o = v * cs + sg * pv * sn;     // even: v*c - pv*s ; odd: v*c + pv*s
                }
                if (isQ)
                    Qo[(((size_t)b * NHD + hh) * SEQL + s) * HDD + d] = f2bf(o);
                else if (isK)
                    Ko[(((size_t)b * KVHD + hh) * SEQL + s) * HDD + d] = f2bf(o);
                else
                    VTo[(((size_t)b * KVHD + hh) * HDD + d) * SEQL + s] = f2bf(o);
            }
        }
    }
}

// ---------------------------------------------------------------------------
// Kernel 2: bf16 MFMA causal flash attention (unchanged from R2 except bf16 AO)
// ---------------------------------------------------------------------------
__global__ __launch_bounds__(256) void attn_mfma_kernel(
    const unsigned short* __restrict__ Q, const unsigned short* __restrict__ K,
    const unsigned short* __restrict__ VT, unsigned short* __restrict__ AO)
{
    __shared__ unsigned short Ks[64][104];
    __shared__ unsigned short VTs[96][72];
    __shared__ unsigned short Ps[4][16][72];

    const int tid  = threadIdx.x;
    const int w    = tid >> 6;
    const int lane = tid & 63;
    const int l16  = lane & 15;
    const int quad = lane >> 4;
    const int qt   = (gridDim.x - 1) - blockIdx.x;
    const int h    = blockIdx.y;
    const int b    = blockIdx.z;
    const int kvh  = h / GRPS;

    const unsigned short* Qbase  = Q  + (((size_t)b * NHD  + h)   * SEQL) * HDD;
    const unsigned short* Kbase  = K  + (((size_t)b * KVHD + kvh) * SEQL) * HDD;
    const unsigned short* VTbase = VT + (((size_t)b * KVHD + kvh) * HDD)  * SEQL;

    bf16x8 qf[3];
    {
        const int qrow = qt * 64 + w * 16 + l16;
        const unsigned short* qp = Qbase + (size_t)qrow * HDD + quad * 8;
        qf[0] = *(const bf16x8*)(qp);
        qf[1] = *(const bf16x8*)(qp + 32);
        qf[2] = *(const bf16x8*)(qp + 64);
    }

    float m_r[4], l_r[4];
    #pragma unroll
    for (int r = 0; r < 4; r++) { m_r[r] = -1e30f; l_r[r] = 0.0f; }
    f32x4 oacc[6];
    #pragma unroll
    for (int n = 0; n < 6; n++) oacc[n] = (f32x4){0.f, 0.f, 0.f, 0.f};

    const int nkb = qt + 1;
    for (int kb = 0; kb < nkb; kb++) {
        const int k0 = kb * 64;
        {
            const int r = tid >> 2, c = (tid & 3) * 24;
            const unsigned short* src = Kbase + (size_t)(k0 + r) * HDD + c;
            unsigned short* dst = &Ks[r][c];
            *(bf16x8*)(dst)      = *(const bf16x8*)(src);
            *(bf16x8*)(dst + 8)  = *(const bf16x8*)(src + 8);
            *(bf16x8*)(dst + 16) = *(const bf16x8*)(src + 16);
        }
        {
            const int rr = tid >> 3, c = (tid & 7) * 8;
            #pragma unroll
            for (int p = 0; p < 3; p++) {
                const int r = p * 32 + rr;
                *(bf16x8*)(&VTs[r][c]) =
                    *(const bf16x8*)(VTbase + (size_t)r * SEQL + k0 + c);
            }
        }
        __syncthreads();

        f32x4 s[4];
        #pragma unroll
        for (int n = 0; n < 4; n++) {
            const unsigned short* kr = &Ks[n * 16 + l16][quad * 8];
            bf16x8 b0 = *(const bf16x8*)(kr);
            bf16x8 b1 = *(const bf16x8*)(kr + 32);
            bf16x8 b2 = *(const bf16x8*)(kr + 64);
            f32x4 acc = (f32x4){0.f, 0.f, 0.f, 0.f};
            acc = __builtin_amdgcn_mfma_f32_16x16x32_bf16(qf[0], b0, acc, 0, 0, 0);
            acc = __builtin_amdgcn_mfma_f32_16x16x32_bf16(qf[1], b1, acc, 0, 0, 0);
            acc = __builtin_amdgcn_mfma_f32_16x16x32_bf16(qf[2], b2, acc, 0, 0, 0);
            s[n] = acc;
        }

        const int qabs = qt * 64 + w * 16 + quad * 4;
        const bool diag = (kb == qt);
        float alpha[4];
        #pragma unroll
        for (int r = 0; r < 4; r++) {
            float sv[4];
            #pragma unroll
            for (int n = 0; n < 4; n++) {
                float v = s[n][r] * SCALE;
                if (diag && (k0 + n * 16 + l16 > qabs + r)) v = -1e30f;
                sv[n] = v;
            }
            float mx = fmaxf(fmaxf(sv[0], sv[1]), fmaxf(sv[2], sv[3]));
            #pragma unroll
            for (int off = 1; off < 16; off <<= 1)
                mx = fmaxf(mx, __shfl_xor(mx, off, 64));
            const float mnew = fmaxf(m_r[r], mx);
            const float al = __expf(m_r[r] - mnew);
            float p[4], sum = 0.0f;
            #pragma unroll
            for (int n = 0; n < 4; n++) { p[n] = __expf(sv[n] - mnew); sum += p[n]; }
            #pragma unroll
            for (int off = 1; off < 16; off <<= 1)
                sum += __shfl_xor(sum, off, 64);
            l_r[r] = l_r[r] * al + sum;
            m_r[r] = mnew;
            alpha[r] = al;
            #pragma unroll
            for (int n = 0; n < 4; n++)
                Ps[w][quad * 4 + r][n * 16 + l16] = f2bf(p[n]);
        }
        __builtin_amdgcn_wave_barrier();

        bf16x8 pa0 = *(const bf16x8*)(&Ps[w][l16][quad * 8]);
        bf16x8 pa1 = *(const bf16x8*)(&Ps[w][l16][32 + quad * 8]);
        #pragma unroll
        for (int n = 0; n < 6; n++) {
            const unsigned short* vr = &VTs[n * 16 + l16][quad * 8];
            bf16x8 vb0 = *(const bf16x8*)(vr);
            bf16x8 vb1 = *(const bf16x8*)(vr + 32);
            f32x4 acc = oacc[n];
            #pragma unroll
            for (int r = 0; r < 4; r++) acc[r] *= alpha[r];
            acc = __builtin_amdgcn_mfma_f32_16x16x32_bf16(pa0, vb0, acc, 0, 0, 0);
            acc = __builtin_amdgcn_mfma_f32_16x16x32_bf16(pa1, vb1, acc, 0, 0, 0);
            oacc[n] = acc;
        }
        __syncthreads();
    }

    float inv_l[4];
    #pragma unroll
    for (int r = 0; r < 4; r++) inv_l[r] = 1.0f / l_r[r];
    const int srow = qt * 64 + w * 16 + quad * 4;
    #pragma unroll
    for (int n = 0; n < 6; n++) {
        #pragma unroll
        for (int r = 0; r < 4; r++) {
            AO[((size_t)b * SEQL + srow + r) * DIMD + h * HDD + n * 16 + l16] =
                f2bf(oacc[n][r] * inv_l[r]);
        }
    }
}

// ---------------------------------------------------------------------------
// Kernel 3: output projection, bf16 MFMA (same core), fp32 bias + fp32 out.
// ---------------------------------------------------------------------------
__global__ __launch_bounds__(256) void out_mfma_kernel(
    const unsigned short* __restrict__ Ab, const unsigned short* __restrict__ Wb,
    const float* __restrict__ wob, float* __restrict__ out)
{
    __shared__ __align__(16) unsigned short As[128 * 32];
    __shared__ __align__(16) unsigned short Bs[128 * 32];

    const int tid  = threadIdx.x;
    const int w    = tid >> 6;
    const int lane = tid & 63;
    const int l16  = lane & 15;
    const int quad = lane >> 4;
    const int wm   = w >> 1, wn = w & 1;
    const int m0   = blockIdx.y * 128;
    const int n0   = blockIdx.x * 128;

    const unsigned short* Abase = Ab + (size_t)m0 * DIMD;
    const unsigned short* Bbase = Wb + (size_t)n0 * DIMD;

    const int srow = w * 16 + (lane >> 2);
    const int scol = (lane & 3) * 8;

    f32x4 acc[4][4];
    #pragma unroll
    for (int mi = 0; mi < 4; mi++)
        #pragma unroll
        for (int ni = 0; ni < 4; ni++) acc[mi][ni] = (f32x4){0.f, 0.f, 0.f, 0.f};

    for (int k0 = 0; k0 < DIMD; k0 += 32) {
        gload16(Abase + (size_t)srow        * DIMD + k0 + scol, &As[w * 512]);
        gload16(Abase + (size_t)(srow + 64) * DIMD + k0 + scol, &As[2048 + w * 512]);
        gload16(Bbase + (size_t)srow        * DIMD + k0 + scol, &Bs[w * 512]);
        gload16(Bbase + (size_t)(srow + 64) * DIMD + k0 + scol, &Bs[2048 + w * 512]);
        __syncthreads();
        bf16x8 af[4], bfr[4];
        #pragma unroll
        for (int mi = 0; mi < 4; mi++)
            af[mi] = *(const bf16x8*)&As[(wm * 64 + mi * 16 + l16) * 32 + quad * 8];
        #pragma unroll
        for (int ni = 0; ni < 4; ni++)
            bfr[ni] = *(const bf16x8*)&Bs[(wn * 64 + ni * 16 + l16) * 32 + quad * 8];
        #pragma unroll
        for (int mi = 0; mi < 4; mi++)
            #pragma unroll
            for (int ni = 0; ni < 4; ni++)
                acc[mi][ni] = __builtin_amdgcn_mfma_f32_16x16x32_bf16(
                    af[mi], bfr[ni], acc[mi][ni], 0, 0, 0);
        __syncthreads();
    }

    #pragma unroll
    for (int ni = 0; ni < 4; ni++) {
        const int n = n0 + wn * 64 + ni * 16 + l16;
        const float bias = wob[n];
        #pragma unroll
        for (int mi = 0; mi < 4; mi++) {
            #pragma unroll
            for (int r = 0; r < 4; r++) {
                const int m = m0 + wm * 64 + mi * 16 + quad * 4 + r;
                out[(size_t)m * DIMD + n] = acc[mi][ni][r] + bias;
            }
        }
    }
}

// ---------------------------------------------------------------------------
extern "C" void kernel_launch(void* const* d_in, const int* in_sizes, int n_in,
                              void* d_out, int out_size, void* d_ws, size_t ws_size,
                              hipStream_t stream)
{
    const float* x   = (const float*)d_in[0];
    // d_in[1] = mask: exactly triu(-1e9, k=1) -> causal predicate in-kernel
    const float* qw  = (const float*)d_in[2];
    const float* qb  = (const float*)d_in[3];
    const float* kvw = (const float*)d_in[4];
    const float* kvb = (const float*)d_in[5];
    const float* wow = (const float*)d_in[6];
    const float* wob = (const float*)d_in[7];
    const int*   sp  = (const int*)d_in[8];

    const size_t xN   = (size_t)MROWS * DIMD;          // 9,437,184
    const size_t qwN  = (size_t)DIMD * DIMD;           // 1,327,104
    const size_t kvwN = (size_t)2 * KVHD * HDD * DIMD; //   442,368
    const size_t qN   = (size_t)BSZ4 * NHD  * SEQL * HDD;
    const size_t kvN  = (size_t)BSZ4 * KVHD * SEQL * HDD;

    unsigned short* xb   = (unsigned short*)d_ws;
    unsigned short* qwb  = xb   + xN;
    unsigned short* kvwb = qwb  + qwN;
    unsigned short* wowb = kvwb + kvwN;
    unsigned short* Q16  = wowb + qwN;
    unsigned short* K16  = Q16  + qN;
    unsigned short* VT16 = K16  + kvN;
    unsigned short* AO16 = VT16 + kvN;   // total ~69 MB

    cvt_bf16_kernel<<<(int)(xN / 4 + 255) / 256, 256, 0, stream>>>(
        (const float4*)x, (ushort4*)xb, (int)(xN / 4));
    cvt_bf16_kernel<<<(int)(qwN / 4 + 255) / 256, 256, 0, stream>>>(
        (const float4*)qw, (ushort4*)qwb, (int)(qwN / 4));
    cvt_bf16_kernel<<<(int)(kvwN / 4 + 255) / 256, 256, 0, stream>>>(
        (const float4*)kvw, (ushort4*)kvwb, (int)(kvwN / 4));
    cvt_bf16_kernel<<<(int)(qwN / 4 + 255) / 256, 256, 0, stream>>>(
        (const float4*)wow, (ushort4*)wowb, (int)(qwN / 4));

    qkv_mfma_kernel<<<dim3(NQKV / 128, MROWS / 128, 1), 256, 0, stream>>>(
        xb, qwb, kvwb, qb, kvb, sp, Q16, K16, VT16);
    attn_mfma_kernel<<<dim3(SEQL / 64, NHD, BSZ4), 256, 0, stream>>>(
        Q16, K16, VT16, AO16);
    out_mfma_kernel<<<dim3(DIMD / 128, MROWS / 128, 1), 256, 0, stream>>>(
        AO16, wowb, wob, (float*)d_out);
}